// Round 1
// 1333.036 us; speedup vs baseline: 2.1461x; 2.1461x over previous
//
#include <hip/hip_runtime.h>
#include <hip/hip_bf16.h>

// ---------------------------------------------------------------------------
// GINEConv x2 + mean-pool + 3 heads.  f32 pipeline (correctness anchor).
// KEY FACTS (established rounds 0-4): float inputs = f32, OUTPUT = f32.
// Int width runtime-detected (i32 vs i64).
//
// R5 restructure: edge/MLP kernels were LDS-pipe bound (2 ds_read_b32 per k
// per edge ~= 967us model vs 995us measured).  Now: W staged as float4
// (ds_read_b128, 4 k-values per read) and each wave processes 8 edges/nodes
// so one W read feeds 8 dot products.  Broadcast via v_readlane (VALU, no
// LDS traffic).  DS ops per edge: 128 -> 4.
// Pool: batch is SORTED -> run-length accumulate in registers, flush atomics
// only at graph boundaries (~40x fewer atomics).
// ---------------------------------------------------------------------------

typedef __bf16 bf16_t;

#define N_NODES   50000
#define N_EDGES   800000
#define N_GRAPHS  512
#define HID       128
#define EIN       64

// broadcast lane k of v across the wave via v_readlane (no LDS traffic)
#define RL(v, l) __int_as_float(__builtin_amdgcn_readlane(__float_as_int(v), (l)))

__device__ __forceinline__ float ldf(const void* p, size_t i, int f32m) {
    return f32m ? ((const float*)p)[i] : (float)((const bf16_t*)p)[i];
}
__device__ __forceinline__ int ldi(const void* p, size_t i, int i64m) {
    return i64m ? (int)((const long long*)p)[i] : ((const int*)p)[i];
}

// flags[0]=1 if floats are f32; flags[1]=1 if ints are i64.
__global__ void k_detect(const unsigned short* __restrict__ xw,
                         const unsigned int*   __restrict__ eiw,
                         int* __restrict__ flags)
{
    if (threadIdx.x == 0 && blockIdx.x == 0) {
        int sane = 0;
        for (int i = 0; i < 256; ++i) {
            int e = (xw[i] >> 7) & 0xFF;
            if (e >= 100 && e <= 150) ++sane;    // bf16 N(0,1): ~256; f32: ~154
        }
        flags[0] = (sane < 220) ? 1 : 0;
        int nzhigh = 0;
        for (int i = 0; i < 256; ++i)
            if (eiw[2*i + 1] != 0) ++nzhigh;     // i64 ids < 2^32: high words 0
        flags[1] = (nzhigh == 0) ? 1 : 0;
    }
}

// convert x -> f32 workspace, float4 path when already f32
__global__ void k_cvt4(const void* __restrict__ x, float* __restrict__ dst,
                       const int* __restrict__ flags) {
    const int f32m = flags[0];
    size_t i = (size_t)blockIdx.x * 256 + threadIdx.x;     // float4 index
    if (f32m) {
        ((float4*)dst)[i] = ((const float4*)x)[i];
    } else {
        const bf16_t* s = (const bf16_t*)x;
        float4 v;
        v.x = (float)s[4*i+0]; v.y = (float)s[4*i+1];
        v.z = (float)s[4*i+2]; v.w = (float)s[4*i+3];
        ((float4*)dst)[i] = v;
    }
}

__global__ void k_copy4(const float* __restrict__ s, float* __restrict__ d) {
    size_t i = (size_t)blockIdx.x * 256 + threadIdx.x;
    ((float4*)d)[i] = ((const float4*)s)[i];
}

// ---------------------------------------------------------------------------
// Fused edge kernel.  Each wave owns 8 edges per grid-stride step.
//   e    = ea[edge] @ ew + eb      (64x128, W as float4 in LDS)
//   m    = relu(Xg[src] + e)
//   ag[dst] += m                   (device atomics)
// LDS: Wq[k4][c] = {W[4k4+0][c], W[4k4+1][c], W[4k4+2][c], W[4k4+3][c]}
// 8 edges per wave => each ds_read_b128 feeds 8 fmaf chains.
// ---------------------------------------------------------------------------
__global__ __launch_bounds__(256) void k_edge_s(
        const void* __restrict__ Xg, int xg_ws,   // xg_ws=1: Xg is f32 workspace
        const void* __restrict__ ei,
        const void* __restrict__ ea,
        const void* __restrict__ ew,
        const void* __restrict__ eb,
        float*      __restrict__ ag,
        const int*  __restrict__ flags)
{
    __shared__ float4 Wq[16 * 128];               // 32 KB
    __shared__ float  ebs[HID];
    const int f32m = flags[0];
    const int i64m = flags[1];
    const int xgf  = xg_ws ? 1 : f32m;

    for (int i = threadIdx.x; i < 16 * 128; i += 256) {
        int k4 = i >> 7, c = i & 127;
        float4 w;
        w.x = ldf(ew, (size_t)(4*k4+0)*HID + c, f32m);
        w.y = ldf(ew, (size_t)(4*k4+1)*HID + c, f32m);
        w.z = ldf(ew, (size_t)(4*k4+2)*HID + c, f32m);
        w.w = ldf(ew, (size_t)(4*k4+3)*HID + c, f32m);
        Wq[i] = w;
    }
    for (int i = threadIdx.x; i < HID; i += 256) ebs[i] = ldf(eb, i, f32m);
    __syncthreads();

    const int lane = threadIdx.x & 63;
    const int wid  = (blockIdx.x * 256 + threadIdx.x) >> 6;
    const int nw   = gridDim.x * 4;
    const int ngrp = N_EDGES / 8;                 // 100000 exact

    for (int g = wid; g < ngrp; g += nw) {
        const int e0 = g * 8;
        float av[8]; int src[8], dst[8];
#pragma unroll
        for (int i = 0; i < 8; ++i) {
            av[i]  = ldf(ea, (size_t)(e0+i) * EIN + lane, f32m);
            src[i] = ldi(ei, e0+i, i64m);
            dst[i] = ldi(ei, (size_t)N_EDGES + e0+i, i64m);
        }
        float acc0[8], acc1[8];
#pragma unroll
        for (int i = 0; i < 8; ++i) { acc0[i] = 0.f; acc1[i] = 0.f; }

#pragma unroll 4
        for (int k4 = 0; k4 < 16; ++k4) {
            float4 w0 = Wq[k4 * 128 + lane];
            float4 w1 = Wq[k4 * 128 + 64 + lane];
#pragma unroll
            for (int i = 0; i < 8; ++i) {
                float a0 = RL(av[i], 4*k4+0);
                float a1 = RL(av[i], 4*k4+1);
                float a2 = RL(av[i], 4*k4+2);
                float a3 = RL(av[i], 4*k4+3);
                // strict ascending-k association (matches previous kernel)
                acc0[i] = fmaf(a3, w0.w, fmaf(a2, w0.z, fmaf(a1, w0.y, fmaf(a0, w0.x, acc0[i]))));
                acc1[i] = fmaf(a3, w1.w, fmaf(a2, w1.z, fmaf(a1, w1.y, fmaf(a0, w1.x, acc1[i]))));
            }
        }

#pragma unroll
        for (int i = 0; i < 8; ++i) {
            float x0 = ldf(Xg, (size_t)src[i] * HID + lane,      xgf);
            float x1 = ldf(Xg, (size_t)src[i] * HID + 64 + lane, xgf);
            float v0 = fmaxf(x0 + acc0[i] + ebs[lane],      0.f);
            float v1 = fmaxf(x1 + acc1[i] + ebs[64 + lane], 0.f);
            unsafeAtomicAdd(ag + (size_t)dst[i] * HID + lane,      v0);
            unsafeAtomicAdd(ag + (size_t)dst[i] * HID + 64 + lane, v1);
        }
    }
}

// ---------------------------------------------------------------------------
// Node MLP: Out[n] = relu(A[n] @ W + b).  8 nodes per wave, W float4 in LDS.
// In-place safe: all 8 rows consumed into registers before any write.
// ---------------------------------------------------------------------------
__global__ __launch_bounds__(256) void k_mlp_s(
        const float* __restrict__ A,
        const void*  __restrict__ W,
        const void*  __restrict__ bias,
        float*       __restrict__ Out,
        const int*   __restrict__ flags)
{
    __shared__ float4 Wq[32 * 128];               // 64 KB
    const int f32m = flags[0];
    for (int i = threadIdx.x; i < 32 * 128; i += 256) {
        int k4 = i >> 7, c = i & 127;
        float4 w;
        w.x = ldf(W, (size_t)(4*k4+0)*HID + c, f32m);
        w.y = ldf(W, (size_t)(4*k4+1)*HID + c, f32m);
        w.z = ldf(W, (size_t)(4*k4+2)*HID + c, f32m);
        w.w = ldf(W, (size_t)(4*k4+3)*HID + c, f32m);
        Wq[i] = w;
    }
    __syncthreads();

    const int lane = threadIdx.x & 63;
    const int wid  = (blockIdx.x * 256 + threadIdx.x) >> 6;
    const int nw   = gridDim.x * 4;
    const float b0 = ldf(bias, lane,      f32m);
    const float b1 = ldf(bias, 64 + lane, f32m);
    const int ngrp = N_NODES / 8;                 // 6250 exact

    for (int g = wid; g < ngrp; g += nw) {
        const int n0 = g * 8;
        float alo[8], ahi[8], acc0[8], acc1[8];
#pragma unroll
        for (int i = 0; i < 8; ++i) {
            alo[i] = A[(size_t)(n0+i) * HID + lane];
            ahi[i] = A[(size_t)(n0+i) * HID + 64 + lane];
            acc0[i] = b0; acc1[i] = b1;
        }
        // k = 0..63 (broadcast from alo)
#pragma unroll 4
        for (int k4 = 0; k4 < 16; ++k4) {
            float4 w0 = Wq[k4 * 128 + lane];
            float4 w1 = Wq[k4 * 128 + 64 + lane];
#pragma unroll
            for (int i = 0; i < 8; ++i) {
                float a0 = RL(alo[i], 4*k4+0);
                float a1 = RL(alo[i], 4*k4+1);
                float a2 = RL(alo[i], 4*k4+2);
                float a3 = RL(alo[i], 4*k4+3);
                acc0[i] = fmaf(a3, w0.w, fmaf(a2, w0.z, fmaf(a1, w0.y, fmaf(a0, w0.x, acc0[i]))));
                acc1[i] = fmaf(a3, w1.w, fmaf(a2, w1.z, fmaf(a1, w1.y, fmaf(a0, w1.x, acc1[i]))));
            }
        }
        // k = 64..127 (broadcast from ahi)
#pragma unroll 4
        for (int k4 = 16; k4 < 32; ++k4) {
            float4 w0 = Wq[k4 * 128 + lane];
            float4 w1 = Wq[k4 * 128 + 64 + lane];
#pragma unroll
            for (int i = 0; i < 8; ++i) {
                float a0 = RL(ahi[i], 4*k4+0 - 64);
                float a1 = RL(ahi[i], 4*k4+1 - 64);
                float a2 = RL(ahi[i], 4*k4+2 - 64);
                float a3 = RL(ahi[i], 4*k4+3 - 64);
                acc0[i] = fmaf(a3, w0.w, fmaf(a2, w0.z, fmaf(a1, w0.y, fmaf(a0, w0.x, acc0[i]))));
                acc1[i] = fmaf(a3, w1.w, fmaf(a2, w1.z, fmaf(a1, w1.y, fmaf(a0, w1.x, acc1[i]))));
            }
        }
#pragma unroll
        for (int i = 0; i < 8; ++i) {
            Out[(size_t)(n0+i) * HID + lane]      = fmaxf(acc0[i], 0.f);
            Out[(size_t)(n0+i) * HID + 64 + lane] = fmaxf(acc1[i], 0.f);
        }
    }
}

// ---------------------------------------------------------------------------
// Pool: batch is SORTED.  Block = 128 threads (thread = channel), 64 nodes
// per block; accumulate runs of equal graph id in registers, flush at
// boundaries.  ~40x fewer atomics than per-element.
// ---------------------------------------------------------------------------
__global__ void k_pool_s(const float* __restrict__ X, const void* __restrict__ batch,
                         float* __restrict__ GS, float* __restrict__ GC,
                         const int* __restrict__ flags)
{
    const int i64m = flags[1];
    const int c  = threadIdx.x;                   // 0..127
    const int n0 = blockIdx.x * 64;
    const int nend = (n0 + 64 < N_NODES) ? n0 + 64 : N_NODES;

    int bprev = ldi(batch, n0, i64m);
    float acc = 0.f;
    int   cnt = 0;
    for (int n = n0; n < nend; ++n) {
        int b = ldi(batch, n, i64m);
        if (b != bprev) {
            unsafeAtomicAdd(&GS[(size_t)bprev * HID + c], acc);
            if (c == 0) unsafeAtomicAdd(&GC[bprev], (float)cnt);
            acc = 0.f; cnt = 0; bprev = b;
        }
        acc += X[(size_t)n * HID + c];
        ++cnt;
    }
    unsafeAtomicAdd(&GS[(size_t)bprev * HID + c], acc);
    if (c == 0) unsafeAtomicAdd(&GC[bprev], (float)cnt);
}

// Head: one wave per graph; OUTPUT IS FLOAT32.
__global__ void k_head(const float* __restrict__ GS, const float* __restrict__ GC,
                       const void* __restrict__ fcw, const void* __restrict__ fcb,
                       const void* __restrict__ hSw, const void* __restrict__ hSb,
                       const void* __restrict__ hPw, const void* __restrict__ hPb,
                       const void* __restrict__ hNw, const void* __restrict__ hNb,
                       float* __restrict__ out, const int* __restrict__ flags)
{
    const int f32m = flags[0];
    const int g = blockIdx.x;
    const int lane = threadIdx.x;                 // 64 threads
    const float inv = 1.f / fmaxf(GC[g], 1.f);
    const float g0 = GS[(size_t)g * HID + lane]      * inv;
    const float g1 = GS[(size_t)g * HID + 64 + lane] * inv;

    float acc = 0.f;
    for (int k = 0; k < 64; ++k) {
        float gk = __shfl(g0, k, 64);
        acc += gk * ldf(fcw, k * 64 + lane, f32m);
    }
    for (int k = 0; k < 64; ++k) {
        float gk = __shfl(g1, k, 64);
        acc += gk * ldf(fcw, (64 + k) * 64 + lane, f32m);
    }
    float s = fmaxf(acc + ldf(fcb, lane, f32m), 0.f);

    float pS = s * ldf(hSw, lane, f32m);
    float pP = s * ldf(hPw, lane, f32m);
    float pN = s * ldf(hNw, lane, f32m);
#pragma unroll
    for (int off = 32; off; off >>= 1) {
        pS += __shfl_down(pS, off, 64);
        pP += __shfl_down(pP, off, 64);
        pN += __shfl_down(pN, off, 64);
    }
    if (lane == 0) {
        out[g]                = pS + ldf(hSb, 0, f32m);
        out[N_GRAPHS + g]     = pP + ldf(hPb, 0, f32m);
        out[2 * N_GRAPHS + g] = pN + ldf(hNb, 0, f32m);
    }
}

extern "C" void kernel_launch(void* const* d_in, const int* in_sizes, int n_in,
                              void* d_out, int out_size, void* d_ws, size_t ws_size,
                              hipStream_t stream)
{
    const void* x     = d_in[0];
    const void* ei    = d_in[1];
    const void* ea    = d_in[2];
    const void* batch = d_in[3];
    const void* e1w = d_in[4],  *e1b = d_in[5];
    const void* n1w1= d_in[6],  *n1b1= d_in[7];
    const void* n1w2= d_in[8],  *n1b2= d_in[9];
    const void* e2w = d_in[10], *e2b = d_in[11];
    const void* n2w1= d_in[12], *n2b1= d_in[13];
    const void* n2w2= d_in[14], *n2b2= d_in[15];
    const void* fcw = d_in[16], *fcb = d_in[17];
    const void* hSw = d_in[18], *hSb = d_in[19];
    const void* hPw = d_in[20], *hPb = d_in[21];
    const void* hNw = d_in[22], *hNb = d_in[23];

    float* B1 = (float*)d_ws;                          // 6.4M f32
    float* B2 = B1 + (size_t)N_NODES * HID;            // 6.4M f32
    float* GS = B2 + (size_t)N_NODES * HID;            // 512*128 f32
    float* GC = GS + (size_t)N_GRAPHS * HID;           // 512 f32
    int*   FL = (int*)(GC + N_GRAPHS);                 // 2 ints

    k_detect<<<1, 64, 0, stream>>>((const unsigned short*)x, (const unsigned int*)ei, FL);
    hipMemsetAsync(GS, 0, (N_GRAPHS * HID + N_GRAPHS) * sizeof(float), stream);

    const int NV4_BLKS = (N_NODES * HID / 4) / 256;    // 6250 (exact)

    // Layer 1
    k_cvt4  <<<NV4_BLKS, 256, 0, stream>>>(x, B1, FL);
    k_edge_s<<<1024, 256, 0, stream>>>(x, 0, ei, ea, e1w, e1b, B1, FL);
    k_mlp_s <<<512, 256, 0, stream>>>(B1, n1w1, n1b1, B1, FL);
    k_mlp_s <<<512, 256, 0, stream>>>(B1, n1w2, n1b2, B1, FL);    // B1 = h1

    // Layer 2
    k_copy4 <<<NV4_BLKS, 256, 0, stream>>>(B1, B2);
    k_edge_s<<<1024, 256, 0, stream>>>(B1, 1, ei, ea, e2w, e2b, B2, FL);
    k_mlp_s <<<512, 256, 0, stream>>>(B2, n2w1, n2b1, B2, FL);
    k_mlp_s <<<512, 256, 0, stream>>>(B2, n2w2, n2b2, B2, FL);    // B2 = h2

    // Pool + heads
    k_pool_s<<<(N_NODES + 63) / 64, 128, 0, stream>>>(B2, batch, GS, GC, FL);
    k_head  <<<N_GRAPHS, 64, 0, stream>>>(GS, GC, fcw, fcb, hSw, hSb, hPw, hPb, hNw, hNb,
                                          (float*)d_out, FL);
}

// Round 2
// 1283.110 us; speedup vs baseline: 2.2296x; 1.0389x over previous
//
#include <hip/hip_runtime.h>
#include <hip/hip_bf16.h>

// ---------------------------------------------------------------------------
// GINEConv x2 + mean-pool + 3 heads.  f32 pipeline (correctness anchor).
// KEY FACTS: float inputs = f32, OUTPUT = f32.  Int width runtime-detected.
//
// R5: W as float4 in LDS (ds_read_b128), 8 edges/nodes per wave, v_readlane
// broadcast.  LDS-pipe bound -> VALU/latency.
// R6 (this round): occupancy fix.  Edge kernel was LDS-capped at 16 waves/CU
// (33KB per 256-thr block); MLP at 8 waves/CU (64KB per 256-thr block).
// Bigger blocks amortize the LDS: edge 512 thr x 4 blocks/CU = 32 waves/CU,
// MLP 1024 thr x 2 blocks/CU = 32 waves/CU.  Latency-bound kernels (only
// ~33% per-SIMD VALU issue at 423us) should scale ~2x.
// Also: k_copy4 folded into k_mlp_s via optional second output (saves one
// dispatch + 25MB of traffic).
// ---------------------------------------------------------------------------

typedef __bf16 bf16_t;

#define N_NODES   50000
#define N_EDGES   800000
#define N_GRAPHS  512
#define HID       128
#define EIN       64

// broadcast lane l of v across the wave via v_readlane (no LDS traffic)
#define RL(v, l) __int_as_float(__builtin_amdgcn_readlane(__float_as_int(v), (l)))

__device__ __forceinline__ float ldf(const void* p, size_t i, int f32m) {
    return f32m ? ((const float*)p)[i] : (float)((const bf16_t*)p)[i];
}
__device__ __forceinline__ int ldi(const void* p, size_t i, int i64m) {
    return i64m ? (int)((const long long*)p)[i] : ((const int*)p)[i];
}

// flags[0]=1 if floats are f32; flags[1]=1 if ints are i64.
__global__ void k_detect(const unsigned short* __restrict__ xw,
                         const unsigned int*   __restrict__ eiw,
                         int* __restrict__ flags)
{
    if (threadIdx.x == 0 && blockIdx.x == 0) {
        int sane = 0;
        for (int i = 0; i < 256; ++i) {
            int e = (xw[i] >> 7) & 0xFF;
            if (e >= 100 && e <= 150) ++sane;    // bf16 N(0,1): ~256; f32: ~154
        }
        flags[0] = (sane < 220) ? 1 : 0;
        int nzhigh = 0;
        for (int i = 0; i < 256; ++i)
            if (eiw[2*i + 1] != 0) ++nzhigh;     // i64 ids < 2^32: high words 0
        flags[1] = (nzhigh == 0) ? 1 : 0;
    }
}

// convert x -> f32 workspace, float4 path when already f32
__global__ void k_cvt4(const void* __restrict__ x, float* __restrict__ dst,
                       const int* __restrict__ flags) {
    const int f32m = flags[0];
    size_t i = (size_t)blockIdx.x * 256 + threadIdx.x;     // float4 index
    if (f32m) {
        ((float4*)dst)[i] = ((const float4*)x)[i];
    } else {
        const bf16_t* s = (const bf16_t*)x;
        float4 v;
        v.x = (float)s[4*i+0]; v.y = (float)s[4*i+1];
        v.z = (float)s[4*i+2]; v.w = (float)s[4*i+3];
        ((float4*)dst)[i] = v;
    }
}

// ---------------------------------------------------------------------------
// Fused edge kernel.  Each wave owns 8 edges per grid-stride step.
//   e    = ea[edge] @ ew + eb      (64x128, W as float4 in LDS)
//   m    = relu(Xg[src] + e)
//   ag[dst] += m                   (device atomics)
// 512 threads/block, 33KB LDS -> 4 blocks/CU = 32 waves/CU (full occupancy).
// ---------------------------------------------------------------------------
__global__ __launch_bounds__(512) void k_edge_s(
        const void* __restrict__ Xg, int xg_ws,   // xg_ws=1: Xg is f32 workspace
        const void* __restrict__ ei,
        const void* __restrict__ ea,
        const void* __restrict__ ew,
        const void* __restrict__ eb,
        float*      __restrict__ ag,
        const int*  __restrict__ flags)
{
    __shared__ float4 Wq[16 * 128];               // 32 KB
    __shared__ float  ebs[HID];
    const int f32m = flags[0];
    const int i64m = flags[1];
    const int xgf  = xg_ws ? 1 : f32m;

    for (int i = threadIdx.x; i < 16 * 128; i += 512) {
        int k4 = i >> 7, c = i & 127;
        float4 w;
        w.x = ldf(ew, (size_t)(4*k4+0)*HID + c, f32m);
        w.y = ldf(ew, (size_t)(4*k4+1)*HID + c, f32m);
        w.z = ldf(ew, (size_t)(4*k4+2)*HID + c, f32m);
        w.w = ldf(ew, (size_t)(4*k4+3)*HID + c, f32m);
        Wq[i] = w;
    }
    for (int i = threadIdx.x; i < HID; i += 512) ebs[i] = ldf(eb, i, f32m);
    __syncthreads();

    const int lane = threadIdx.x & 63;
    const int wid  = (blockIdx.x * 512 + threadIdx.x) >> 6;
    const int nw   = gridDim.x * 8;
    const int ngrp = N_EDGES / 8;                 // 100000 exact

    for (int g = wid; g < ngrp; g += nw) {
        const int e0 = g * 8;
        float av[8]; int src[8], dst[8];
#pragma unroll
        for (int i = 0; i < 8; ++i) {
            av[i]  = ldf(ea, (size_t)(e0+i) * EIN + lane, f32m);
            src[i] = ldi(ei, e0+i, i64m);
            dst[i] = ldi(ei, (size_t)N_EDGES + e0+i, i64m);
        }
        float acc0[8], acc1[8];
#pragma unroll
        for (int i = 0; i < 8; ++i) { acc0[i] = 0.f; acc1[i] = 0.f; }

#pragma unroll 4
        for (int k4 = 0; k4 < 16; ++k4) {
            float4 w0 = Wq[k4 * 128 + lane];
            float4 w1 = Wq[k4 * 128 + 64 + lane];
#pragma unroll
            for (int i = 0; i < 8; ++i) {
                float a0 = RL(av[i], 4*k4+0);
                float a1 = RL(av[i], 4*k4+1);
                float a2 = RL(av[i], 4*k4+2);
                float a3 = RL(av[i], 4*k4+3);
                // strict ascending-k association (matches previous kernel)
                acc0[i] = fmaf(a3, w0.w, fmaf(a2, w0.z, fmaf(a1, w0.y, fmaf(a0, w0.x, acc0[i]))));
                acc1[i] = fmaf(a3, w1.w, fmaf(a2, w1.z, fmaf(a1, w1.y, fmaf(a0, w1.x, acc1[i]))));
            }
        }

#pragma unroll
        for (int i = 0; i < 8; ++i) {
            float x0 = ldf(Xg, (size_t)src[i] * HID + lane,      xgf);
            float x1 = ldf(Xg, (size_t)src[i] * HID + 64 + lane, xgf);
            float v0 = fmaxf(x0 + acc0[i] + ebs[lane],      0.f);
            float v1 = fmaxf(x1 + acc1[i] + ebs[64 + lane], 0.f);
            unsafeAtomicAdd(ag + (size_t)dst[i] * HID + lane,      v0);
            unsafeAtomicAdd(ag + (size_t)dst[i] * HID + 64 + lane, v1);
        }
    }
}

// ---------------------------------------------------------------------------
// Node MLP: Out[n] = relu(A[n] @ W + b).  8 nodes per wave, W float4 in LDS.
// 1024 threads/block, 64KB LDS -> 2 blocks/CU = 32 waves/CU (full occupancy).
// In-place safe: all 8 rows consumed into registers before any write.
// Out2 (optional, may be null): duplicate store, folds the inter-layer copy.
// ---------------------------------------------------------------------------
__global__ __launch_bounds__(1024) void k_mlp_s(
        const float* __restrict__ A,
        const void*  __restrict__ W,
        const void*  __restrict__ bias,
        float*       __restrict__ Out,
        float*       __restrict__ Out2,
        const int*   __restrict__ flags)
{
    __shared__ float4 Wq[32 * 128];               // 64 KB
    const int f32m = flags[0];
    for (int i = threadIdx.x; i < 32 * 128; i += 1024) {
        int k4 = i >> 7, c = i & 127;
        float4 w;
        w.x = ldf(W, (size_t)(4*k4+0)*HID + c, f32m);
        w.y = ldf(W, (size_t)(4*k4+1)*HID + c, f32m);
        w.z = ldf(W, (size_t)(4*k4+2)*HID + c, f32m);
        w.w = ldf(W, (size_t)(4*k4+3)*HID + c, f32m);
        Wq[i] = w;
    }
    __syncthreads();

    const int lane = threadIdx.x & 63;
    const int wid  = (blockIdx.x * 1024 + threadIdx.x) >> 6;
    const int nw   = gridDim.x * 16;
    const float b0 = ldf(bias, lane,      f32m);
    const float b1 = ldf(bias, 64 + lane, f32m);
    const int ngrp = N_NODES / 8;                 // 6250 exact

    for (int g = wid; g < ngrp; g += nw) {
        const int n0 = g * 8;
        float alo[8], ahi[8], acc0[8], acc1[8];
#pragma unroll
        for (int i = 0; i < 8; ++i) {
            alo[i] = A[(size_t)(n0+i) * HID + lane];
            ahi[i] = A[(size_t)(n0+i) * HID + 64 + lane];
            acc0[i] = b0; acc1[i] = b1;
        }
        // k = 0..63 (broadcast from alo)
#pragma unroll 4
        for (int k4 = 0; k4 < 16; ++k4) {
            float4 w0 = Wq[k4 * 128 + lane];
            float4 w1 = Wq[k4 * 128 + 64 + lane];
#pragma unroll
            for (int i = 0; i < 8; ++i) {
                float a0 = RL(alo[i], 4*k4+0);
                float a1 = RL(alo[i], 4*k4+1);
                float a2 = RL(alo[i], 4*k4+2);
                float a3 = RL(alo[i], 4*k4+3);
                acc0[i] = fmaf(a3, w0.w, fmaf(a2, w0.z, fmaf(a1, w0.y, fmaf(a0, w0.x, acc0[i]))));
                acc1[i] = fmaf(a3, w1.w, fmaf(a2, w1.z, fmaf(a1, w1.y, fmaf(a0, w1.x, acc1[i]))));
            }
        }
        // k = 64..127 (broadcast from ahi)
#pragma unroll 4
        for (int k4 = 16; k4 < 32; ++k4) {
            float4 w0 = Wq[k4 * 128 + lane];
            float4 w1 = Wq[k4 * 128 + 64 + lane];
#pragma unroll
            for (int i = 0; i < 8; ++i) {
                float a0 = RL(ahi[i], 4*k4+0 - 64);
                float a1 = RL(ahi[i], 4*k4+1 - 64);
                float a2 = RL(ahi[i], 4*k4+2 - 64);
                float a3 = RL(ahi[i], 4*k4+3 - 64);
                acc0[i] = fmaf(a3, w0.w, fmaf(a2, w0.z, fmaf(a1, w0.y, fmaf(a0, w0.x, acc0[i]))));
                acc1[i] = fmaf(a3, w1.w, fmaf(a2, w1.z, fmaf(a1, w1.y, fmaf(a0, w1.x, acc1[i]))));
            }
        }
#pragma unroll
        for (int i = 0; i < 8; ++i) {
            float v0 = fmaxf(acc0[i], 0.f);
            float v1 = fmaxf(acc1[i], 0.f);
            Out[(size_t)(n0+i) * HID + lane]      = v0;
            Out[(size_t)(n0+i) * HID + 64 + lane] = v1;
            if (Out2) {
                Out2[(size_t)(n0+i) * HID + lane]      = v0;
                Out2[(size_t)(n0+i) * HID + 64 + lane] = v1;
            }
        }
    }
}

// ---------------------------------------------------------------------------
// Pool: batch is SORTED.  Block = 128 threads (thread = channel), 64 nodes
// per block; accumulate runs of equal graph id in registers, flush at
// boundaries.
// ---------------------------------------------------------------------------
__global__ void k_pool_s(const float* __restrict__ X, const void* __restrict__ batch,
                         float* __restrict__ GS, float* __restrict__ GC,
                         const int* __restrict__ flags)
{
    const int i64m = flags[1];
    const int c  = threadIdx.x;                   // 0..127
    const int n0 = blockIdx.x * 64;
    const int nend = (n0 + 64 < N_NODES) ? n0 + 64 : N_NODES;

    int bprev = ldi(batch, n0, i64m);
    float acc = 0.f;
    int   cnt = 0;
    for (int n = n0; n < nend; ++n) {
        int b = ldi(batch, n, i64m);
        if (b != bprev) {
            unsafeAtomicAdd(&GS[(size_t)bprev * HID + c], acc);
            if (c == 0) unsafeAtomicAdd(&GC[bprev], (float)cnt);
            acc = 0.f; cnt = 0; bprev = b;
        }
        acc += X[(size_t)n * HID + c];
        ++cnt;
    }
    unsafeAtomicAdd(&GS[(size_t)bprev * HID + c], acc);
    if (c == 0) unsafeAtomicAdd(&GC[bprev], (float)cnt);
}

// Head: one wave per graph; OUTPUT IS FLOAT32.
__global__ void k_head(const float* __restrict__ GS, const float* __restrict__ GC,
                       const void* __restrict__ fcw, const void* __restrict__ fcb,
                       const void* __restrict__ hSw, const void* __restrict__ hSb,
                       const void* __restrict__ hPw, const void* __restrict__ hPb,
                       const void* __restrict__ hNw, const void* __restrict__ hNb,
                       float* __restrict__ out, const int* __restrict__ flags)
{
    const int f32m = flags[0];
    const int g = blockIdx.x;
    const int lane = threadIdx.x;                 // 64 threads
    const float inv = 1.f / fmaxf(GC[g], 1.f);
    const float g0 = GS[(size_t)g * HID + lane]      * inv;
    const float g1 = GS[(size_t)g * HID + 64 + lane] * inv;

    float acc = 0.f;
    for (int k = 0; k < 64; ++k) {
        float gk = __shfl(g0, k, 64);
        acc += gk * ldf(fcw, k * 64 + lane, f32m);
    }
    for (int k = 0; k < 64; ++k) {
        float gk = __shfl(g1, k, 64);
        acc += gk * ldf(fcw, (64 + k) * 64 + lane, f32m);
    }
    float s = fmaxf(acc + ldf(fcb, lane, f32m), 0.f);

    float pS = s * ldf(hSw, lane, f32m);
    float pP = s * ldf(hPw, lane, f32m);
    float pN = s * ldf(hNw, lane, f32m);
#pragma unroll
    for (int off = 32; off; off >>= 1) {
        pS += __shfl_down(pS, off, 64);
        pP += __shfl_down(pP, off, 64);
        pN += __shfl_down(pN, off, 64);
    }
    if (lane == 0) {
        out[g]                = pS + ldf(hSb, 0, f32m);
        out[N_GRAPHS + g]     = pP + ldf(hPb, 0, f32m);
        out[2 * N_GRAPHS + g] = pN + ldf(hNb, 0, f32m);
    }
}

extern "C" void kernel_launch(void* const* d_in, const int* in_sizes, int n_in,
                              void* d_out, int out_size, void* d_ws, size_t ws_size,
                              hipStream_t stream)
{
    const void* x     = d_in[0];
    const void* ei    = d_in[1];
    const void* ea    = d_in[2];
    const void* batch = d_in[3];
    const void* e1w = d_in[4],  *e1b = d_in[5];
    const void* n1w1= d_in[6],  *n1b1= d_in[7];
    const void* n1w2= d_in[8],  *n1b2= d_in[9];
    const void* e2w = d_in[10], *e2b = d_in[11];
    const void* n2w1= d_in[12], *n2b1= d_in[13];
    const void* n2w2= d_in[14], *n2b2= d_in[15];
    const void* fcw = d_in[16], *fcb = d_in[17];
    const void* hSw = d_in[18], *hSb = d_in[19];
    const void* hPw = d_in[20], *hPb = d_in[21];
    const void* hNw = d_in[22], *hNb = d_in[23];

    float* B1 = (float*)d_ws;                          // 6.4M f32
    float* B2 = B1 + (size_t)N_NODES * HID;            // 6.4M f32
    float* GS = B2 + (size_t)N_NODES * HID;            // 512*128 f32
    float* GC = GS + (size_t)N_GRAPHS * HID;           // 512 f32
    int*   FL = (int*)(GC + N_GRAPHS);                 // 2 ints

    k_detect<<<1, 64, 0, stream>>>((const unsigned short*)x, (const unsigned int*)ei, FL);
    hipMemsetAsync(GS, 0, (N_GRAPHS * HID + N_GRAPHS) * sizeof(float), stream);

    const int NV4_BLKS = (N_NODES * HID / 4) / 256;    // 6250 (exact)

    // Layer 1
    k_cvt4  <<<NV4_BLKS, 256, 0, stream>>>(x, B1, FL);
    k_edge_s<<<1024, 512, 0, stream>>>(x, 0, ei, ea, e1w, e1b, B1, FL);
    k_mlp_s <<<512, 1024, 0, stream>>>(B1, n1w1, n1b1, B1, nullptr, FL);
    k_mlp_s <<<512, 1024, 0, stream>>>(B1, n1w2, n1b2, B1, B2, FL);   // B1 = h1, B2 = copy

    // Layer 2
    k_edge_s<<<1024, 512, 0, stream>>>(B1, 1, ei, ea, e2w, e2b, B2, FL);
    k_mlp_s <<<512, 1024, 0, stream>>>(B2, n2w1, n2b1, B2, nullptr, FL);
    k_mlp_s <<<512, 1024, 0, stream>>>(B2, n2w2, n2b2, B2, nullptr, FL);  // B2 = h2

    // Pool + heads
    k_pool_s<<<(N_NODES + 63) / 64, 128, 0, stream>>>(B2, batch, GS, GC, FL);
    k_head  <<<N_GRAPHS, 64, 0, stream>>>(GS, GC, fcw, fcb, hSw, hSb, hPw, hPb, hNw, hNb,
                                          (float*)d_out, FL);
}